// Round 10
// baseline (551.791 us; speedup 1.0000x reference)
//
#include <hip/hip_runtime.h>
#include <hip/hip_bf16.h>

// GATv2 x3 layers, MI355X. f32 in/out; edge_index int32.
// R22 = R21 resubmitted (previous run died to container failure; code audit
// found no fault: ws 35.58MB == R19 envelope, 640-thr k_agg legal, no OOB).
// R21: R19 base (best: 471us) with k_agg parallelized 2x: 640-thr blocks,
// 2 waves per head (parity-split 4-edge chunks) -> per-wave latency chain
// halves; LDS reduce combines partials (acc per-lane, dn uniform), per-head
// division in the final wave. k_wet hoisted to ONE pre-loop dispatch for all
// 3 layers (Wpk[3]). k_score/k_xl/setup byte-identical to R19.
// R20 lesson: fusion thrashes L2 (all heads per block) + per-edge butterfly
// tax; thread-per-(edge,head) k_score + head-clustered XCD map is the
// confirmed structure.

#define NN 10000    // nodes
#define NE 200000   // edges
#define ND 128      // node dim (layer 0 input)
#define ED 16       // edge dim
#define CD 64       // conv dim (per head)
#define NH 5        // heads
#define HC 320      // NH*CD
#define EF 210000   // NE + NN (with self loops)
#define EFP 210048  // EF padded to 64
#define NEG 0.2f
#define PB 824      // k_score p-blocks per head (824*256 >= EF)
#define TOTB 4120   // PB*NH total k_score blocks = 8 XCDs * 515
#define PERX 515    // k_score work items per XCD

typedef float f2 __attribute__((ext_vector_type(2)));

// ---- CSR build: count ----
__global__ void k_count(const int* __restrict__ dst, int* __restrict__ deg) {
  int e = blockIdx.x * blockDim.x + threadIdx.x;
  if (e >= NE) return;
  atomicAdd(&deg[dst[e]], 1);
}

// ---- CSR build: exclusive scan (single block, 1024 threads x 10 elems) ----
__global__ __launch_bounds__(1024) void k_scan(const int* __restrict__ deg,
                                               int* __restrict__ rowptr) {
  __shared__ int part[1024];
  int t = threadIdx.x;
  int base = t * 10;
  int local[10];
  int s = 0;
  #pragma unroll
  for (int j = 0; j < 10; j++) {
    int i = base + j;
    local[j] = (i < NN) ? deg[i] : 0;
    s += local[j];
  }
  part[t] = s;
  __syncthreads();
  for (int off = 1; off < 1024; off <<= 1) {
    int v = (t >= off) ? part[t - off] : 0;
    __syncthreads();
    part[t] += v;
    __syncthreads();
  }
  int prefix = (t > 0) ? part[t - 1] : 0;
  #pragma unroll
  for (int j = 0; j < 10; j++) {
    int i = base + j;
    if (i < NN) rowptr[i] = prefix;
    prefix += local[j];
  }
  if (t == 1023) rowptr[NN] = prefix;
}

// ---- CSR build: fill ----
__global__ void k_fill(const int* __restrict__ ei, const int* __restrict__ rowptr,
                       int* __restrict__ cursor, int* __restrict__ csr_eid,
                       int* __restrict__ csr_src, int* __restrict__ csr_dst) {
  int e = blockIdx.x * blockDim.x + threadIdx.x;
  if (e >= NE) return;
  int d = ei[NE + e];
  int slot = atomicAdd(&cursor[d], 1);
  int pos = rowptr[d] + slot;
  csr_eid[pos] = e;
  csr_src[pos] = ei[e];
  csr_dst[pos] = d;
}

// ---- ea_csr[p] = edge attrs permuted into CSR order (real edges only) ----
__global__ void k_eacsr(const int* __restrict__ csr_eid, const float* __restrict__ eattr,
                        float* __restrict__ ea_csr) {
  int idx = blockIdx.x * blockDim.x + threadIdx.x;  // (p, quad)
  if (idx >= NE * 4) return;
  int p = idx >> 2, q = idx & 3;
  const float4* sp = (const float4*)(eattr + (size_t)csr_eid[p] * ED);
  ((float4*)(ea_csr + (size_t)p * ED))[q] = sp[q];
}

// ---- loop_attr = mean of incoming edge_attr; reads ea_csr CONTIGUOUSLY ----
__global__ __launch_bounds__(256) void k_loopattr(const float* __restrict__ ea_csr,
                                                  const int* __restrict__ rowptr,
                                                  float* __restrict__ loop_attr) {
  int wave = threadIdx.x >> 6, lane = threadIdx.x & 63;
  int d = blockIdx.x * 4 + wave;
  if (d >= NN) return;
  int g = lane >> 4, k = lane & 15;
  int b = rowptr[d], n = rowptr[d + 1] - b;
  float s = 0.f;
  for (int i = g; i < n; i += 4)
    s += ea_csr[(size_t)(b + i) * ED + k];   // contiguous CSR rows
  s += __shfl_xor(s, 16, 64);
  s += __shfl_xor(s, 32, 64);
  if (g == 0) loop_attr[d * ED + k] = s / fmaxf((float)n, 1.0f);
}

// ---- Wpk for ALL 3 layers in one dispatch ----
// Wpk[l][((h*32 + cp)*16 + k)*2 + j] = We_l[k][h*64 + 2*cp + j]
__global__ void k_wet3(const float* __restrict__ We0, const float* __restrict__ We1,
                       const float* __restrict__ We2, float* __restrict__ Wpk) {
  int i = blockIdx.x * blockDim.x + threadIdx.x;
  if (i >= 3 * ED * HC) return;
  int l = i / (ED * HC);
  int r = i - l * (ED * HC);
  const float* We = (l == 0) ? We0 : (l == 1) ? We1 : We2;
  int j  = r & 1;
  int k  = (r >> 1) & 15;
  int cp = (r >> 5) & 31;
  int h  = r >> 10;
  Wpk[i] = We[k * HC + h * CD + cp * 2 + j];
}

// ---- xl = h @ Wl + bl  (node-major xl[node][hc], contiguous 1280B rows) ----
template <int D>
__global__ __launch_bounds__(320) void k_xl(const float* __restrict__ h,
                                            const float* __restrict__ Wl,
                                            const float* __restrict__ bl,
                                            float* __restrict__ xl) {
  constexpr int NPB = 8;
  int node0 = blockIdx.x * NPB;
  int t = threadIdx.x;  // output column 0..319
  float acc[NPB];
  #pragma unroll
  for (int i = 0; i < NPB; i++) acc[i] = 0.f;
  for (int k = 0; k < D; k += 4) {
    float w0 = Wl[(k + 0) * HC + t];
    float w1 = Wl[(k + 1) * HC + t];
    float w2 = Wl[(k + 2) * HC + t];
    float w3 = Wl[(k + 3) * HC + t];
    #pragma unroll
    for (int i = 0; i < NPB; i++) {
      float4 hv = *(const float4*)(h + (size_t)(node0 + i) * D + k);
      acc[i] += hv.x * w0 + hv.y * w1 + hv.z * w2 + hv.w * w3;
    }
  }
  float bv = bl[t];
  #pragma unroll
  for (int i = 0; i < NPB; i++)
    xl[(size_t)(node0 + i) * HC + t] = acc[i] + bv;
}

// ---- scores: ONE THREAD PER (EDGE, HEAD); writes w = exp(clamped score).
// R14 packed body; node-major xl addressing; head-clustered XCD mapping
// (per-XCD line working set = one head's 2.56MB of lines -> L2-resident).
__global__ __launch_bounds__(256) void k_score(
    const int* __restrict__ csr_src, const int* __restrict__ csr_dst,
    const float* __restrict__ ea_csr, const float* __restrict__ loop_attr,
    const float* __restrict__ xl, const float* __restrict__ Wpk,
    const float* __restrict__ att, float* __restrict__ wP) {
  int bid = blockIdx.x;                       // 0..TOTB-1
  int w = (bid & 7) * PERX + (bid >> 3);      // work item, contiguous per XCD
  int h = w / PB;                             // head (uniform, magic-div)
  int lb = w - h * PB;                        // p-slice within head
  int p = lb * 256 + threadIdx.x;
  if (p >= EF) return;
  int s, d;
  const float* ea;
  if (p < NE) { s = csr_src[p]; d = csr_dst[p]; ea = ea_csr + (size_t)p * ED; }
  else        { s = d = p - NE; ea = loop_attr + (size_t)(p - NE) * ED; }
  float eas[16];
  {
    const float4* q = (const float4*)ea;
    float4 t0 = q[0], t1 = q[1], t2 = q[2], t3 = q[3];
    eas[0] = t0.x;  eas[1] = t0.y;  eas[2] = t0.z;  eas[3] = t0.w;
    eas[4] = t1.x;  eas[5] = t1.y;  eas[6] = t1.z;  eas[7] = t1.w;
    eas[8] = t2.x;  eas[9] = t2.y;  eas[10] = t2.z; eas[11] = t2.w;
    eas[12] = t3.x; eas[13] = t3.y; eas[14] = t3.z; eas[15] = t3.w;
  }
  const float* xsrow = xl + (size_t)s * HC + h * CD;   // node-major
  const float* xdrow = xl + (size_t)d * HC + h * CD;
  const f2* wp = (const f2*)Wpk + (size_t)h * (CD / 2) * ED;  // [32 pairs][16 k]
  const f2* ap = (const f2*)(att + (size_t)h * CD);           // pairs contiguous
  f2 sc2 = {0.f, 0.f};
  const f2 zero = {0.f, 0.f};
  #pragma unroll 4
  for (int cb = 0; cb < CD; cb += 4) {  // 2 channel-pairs per iter, 16 iters
    int cp = cb >> 1;
    float4 xs4 = *(const float4*)(xsrow + cb);
    float4 xd4 = *(const float4*)(xdrow + cb);
    const f2* w0 = wp + (size_t)cp * ED;
    const f2* w1 = w0 + ED;
    f2 z0 = f2{xs4.x, xs4.y} + f2{xd4.x, xd4.y};   // v_pk_add_f32
    f2 z1 = f2{xs4.z, xs4.w} + f2{xd4.z, xd4.w};
    #pragma unroll
    for (int k = 0; k < ED; k++) {                 // 2x v_pk_fma_f32 per k
      z0 += w0[k] * eas[k];
      z1 += w1[k] * eas[k];
    }
    // leaky: max(z,0) + NEG*min(z,0)  (packed, branchless, exact)
    z0 = __builtin_elementwise_max(z0, zero) + NEG * __builtin_elementwise_min(z0, zero);
    z1 = __builtin_elementwise_max(z1, zero) + NEG * __builtin_elementwise_min(z1, zero);
    sc2 += z0 * ap[cp];
    sc2 += z1 * ap[cp + 1];
  }
  float sc = sc2.x + sc2.y;
  sc = fminf(fmaxf(sc, -60.f), 60.f);  // clamp never binds for sane inputs
  wP[(size_t)h * EFP + p] = __expf(sc);
}

// ---- aggregation: block per node, TWO waves per head (parity-split edges) --
// Per-wave latency chain halves vs one-wave-per-head; LDS combines partials.
__global__ __launch_bounds__(640) void k_agg(
    const int* __restrict__ csr_src, const int* __restrict__ rowptr,
    const float* __restrict__ wP, const float* __restrict__ xl,
    const float* __restrict__ bias, float* __restrict__ out) {
  __shared__ float s_v[2 * NH][CD];
  __shared__ float s_dn[2 * NH];
  int w = threadIdx.x >> 6, lane = threadIdx.x & 63;  // w = 0..9
  int h = w >> 1, par = w & 1;
  int d = blockIdx.x;
  int b = rowptr[d], pe = rowptr[d + 1];
  int n = pe - b;
  const float* sp = wP + (size_t)h * EFP;
  const float* xlh = xl + h * CD + lane;               // node-major layout
  float dn = 0.f, acc = 0.f;
  if (par == 0) {  // self loop on even wave
    float w0 = sp[NE + d];
    dn = w0;
    acc = w0 * xlh[(size_t)d * HC];
  }
  // 4-edge chunks, parity-interleaved between the head's two waves
  int nch = (n + 3) >> 2;
  for (int ci = par; ci < nch; ci += 2) {
    int p0 = b + ci * 4;
    if (pe - p0 >= 4) {
      int s0 = csr_src[p0], s1 = csr_src[p0 + 1];
      int s2 = csr_src[p0 + 2], s3 = csr_src[p0 + 3];
      float w0 = sp[p0], w1 = sp[p0 + 1], w2 = sp[p0 + 2], w3 = sp[p0 + 3];
      float x0 = xlh[(size_t)s0 * HC];
      float x1 = xlh[(size_t)s1 * HC];
      float x2 = xlh[(size_t)s2 * HC];
      float x3 = xlh[(size_t)s3 * HC];
      dn += (w0 + w1) + (w2 + w3);
      acc += w0 * x0 + w1 * x1 + w2 * x2 + w3 * x3;
    } else {
      for (int p = p0; p < pe; p++) {
        int s0 = csr_src[p];
        float w0 = sp[p];
        dn += w0;
        acc += w0 * xlh[(size_t)s0 * HC];
      }
    }
  }
  s_v[w][lane] = acc;
  if (lane == 0) s_dn[w] = dn;
  __syncthreads();
  if (w == 0) {
    float v = 0.f;
    #pragma unroll
    for (int hh = 0; hh < NH; hh++) {
      float dsum = s_dn[2 * hh] + s_dn[2 * hh + 1];
      v += (s_v[2 * hh][lane] + s_v[2 * hh + 1][lane]) / dsum;
    }
    v = v * (1.0f / NH) + bias[lane];
    v = v > 0.f ? v : expm1f(v);
    out[(size_t)d * CD + lane] = v;
  }
}

static inline size_t aln(size_t x) { return (x + 255) & ~(size_t)255; }

extern "C" void kernel_launch(void* const* d_in, const int* in_sizes, int n_in,
                              void* d_out, int out_size, void* d_ws, size_t ws_size,
                              hipStream_t stream) {
  const float* x = (const float*)d_in[0];
  const int* ei = (const int*)d_in[1];      // [2, NE]: src row then dst row
  const float* eattr = (const float*)d_in[2];

  char* w = (char*)d_ws;
  int* degi      = (int*)w;                 w += aln(NN * 4);
  int* cursor    = (int*)w;                 w += aln(NN * 4);
  int* rowptr    = (int*)w;                 w += aln((NN + 1) * 4);
  int* csr_eid   = (int*)w;                 w += aln((size_t)NE * 4);
  int* csr_src   = (int*)w;                 w += aln((size_t)NE * 4);
  int* csr_dst   = (int*)w;                 w += aln((size_t)NE * 4);
  float* loop_attr = (float*)w;             w += aln((size_t)NN * ED * 4);
  float* ea_csr  = (float*)w;               w += aln((size_t)NE * ED * 4);
  float* xl      = (float*)w;               w += aln((size_t)NN * HC * 4);
  float* wPbuf   = (float*)w;               w += aln((size_t)NH * EFP * 4);
  float* Wpk     = (float*)w;               w += aln((size_t)3 * ED * HC * 4);
  float* hbuf    = (float*)w;               w += aln((size_t)NN * CD * 4);

  // graph structure + permuted edge attrs + all-layer Wpk (layer-invariant)
  hipMemsetAsync(degi, 0, NN * 4, stream);
  hipMemsetAsync(cursor, 0, NN * 4, stream);
  k_count<<<(NE + 255) / 256, 256, 0, stream>>>(ei + NE, degi);
  k_scan<<<1, 1024, 0, stream>>>(degi, rowptr);
  k_fill<<<(NE + 255) / 256, 256, 0, stream>>>(ei, rowptr, cursor, csr_eid, csr_src, csr_dst);
  k_eacsr<<<(NE * 4 + 255) / 256, 256, 0, stream>>>(csr_eid, eattr, ea_csr);
  k_loopattr<<<(NN + 3) / 4, 256, 0, stream>>>(ea_csr, rowptr, loop_attr);
  k_wet3<<<(3 * ED * HC + 255) / 256, 256, 0, stream>>>(
      (const float*)d_in[5], (const float*)d_in[10], (const float*)d_in[15], Wpk);

  for (int l = 0; l < 3; l++) {
    const float* Wl  = (const float*)d_in[3 + 5 * l];
    const float* bl  = (const float*)d_in[4 + 5 * l];
    const float* att = (const float*)d_in[6 + 5 * l];
    const float* b   = (const float*)d_in[7 + 5 * l];

    if (l == 0) k_xl<ND><<<NN / 8, 320, 0, stream>>>(x, Wl, bl, xl);
    else        k_xl<CD><<<NN / 8, 320, 0, stream>>>(hbuf, Wl, bl, xl);

    k_score<<<TOTB, 256, 0, stream>>>(csr_src, csr_dst, ea_csr, loop_attr,
                                      xl, Wpk + (size_t)l * ED * HC, att, wPbuf);

    float* dst_out = (l < 2) ? hbuf : (float*)d_out;
    k_agg<<<NN, 640, 0, stream>>>(csr_src, rowptr, wPbuf, xl, b, dst_out);
  }
}

// Round 11
// 461.573 us; speedup vs baseline: 1.1955x; 1.1955x over previous
//
#include <hip/hip_runtime.h>
#include <hip/hip_bf16.h>

// GATv2 x3 layers, MI355X. f32 in/out; edge_index int32.
// R23: k_agg back to R19's 320-thr block-per-node/wave-per-head shape, but
// with 8-wide explicit load batching: 8 src + 8 w + 8 xs gathers issued into
// named registers before any use -> 8 gathers in flight per wave (R22 showed
// VGPR=16: the old 4-wide loop serialized on register reuse). R22's 640-thr
// parity split REGRESSED (64.7us vs ~36 inferred for R19) - reverted.
// k_score/k_xl/setup/k_wet3 byte-identical to R22.

#define NN 10000    // nodes
#define NE 200000   // edges
#define ND 128      // node dim (layer 0 input)
#define ED 16       // edge dim
#define CD 64       // conv dim (per head)
#define NH 5        // heads
#define HC 320      // NH*CD
#define EF 210000   // NE + NN (with self loops)
#define EFP 210048  // EF padded to 64
#define NEG 0.2f
#define PB 824      // k_score p-blocks per head (824*256 >= EF)
#define TOTB 4120   // PB*NH total k_score blocks = 8 XCDs * 515
#define PERX 515    // k_score work items per XCD

typedef float f2 __attribute__((ext_vector_type(2)));

// ---- CSR build: count ----
__global__ void k_count(const int* __restrict__ dst, int* __restrict__ deg) {
  int e = blockIdx.x * blockDim.x + threadIdx.x;
  if (e >= NE) return;
  atomicAdd(&deg[dst[e]], 1);
}

// ---- CSR build: exclusive scan (single block, 1024 threads x 10 elems) ----
__global__ __launch_bounds__(1024) void k_scan(const int* __restrict__ deg,
                                               int* __restrict__ rowptr) {
  __shared__ int part[1024];
  int t = threadIdx.x;
  int base = t * 10;
  int local[10];
  int s = 0;
  #pragma unroll
  for (int j = 0; j < 10; j++) {
    int i = base + j;
    local[j] = (i < NN) ? deg[i] : 0;
    s += local[j];
  }
  part[t] = s;
  __syncthreads();
  for (int off = 1; off < 1024; off <<= 1) {
    int v = (t >= off) ? part[t - off] : 0;
    __syncthreads();
    part[t] += v;
    __syncthreads();
  }
  int prefix = (t > 0) ? part[t - 1] : 0;
  #pragma unroll
  for (int j = 0; j < 10; j++) {
    int i = base + j;
    if (i < NN) rowptr[i] = prefix;
    prefix += local[j];
  }
  if (t == 1023) rowptr[NN] = prefix;
}

// ---- CSR build: fill ----
__global__ void k_fill(const int* __restrict__ ei, const int* __restrict__ rowptr,
                       int* __restrict__ cursor, int* __restrict__ csr_eid,
                       int* __restrict__ csr_src, int* __restrict__ csr_dst) {
  int e = blockIdx.x * blockDim.x + threadIdx.x;
  if (e >= NE) return;
  int d = ei[NE + e];
  int slot = atomicAdd(&cursor[d], 1);
  int pos = rowptr[d] + slot;
  csr_eid[pos] = e;
  csr_src[pos] = ei[e];
  csr_dst[pos] = d;
}

// ---- ea_csr[p] = edge attrs permuted into CSR order (real edges only) ----
__global__ void k_eacsr(const int* __restrict__ csr_eid, const float* __restrict__ eattr,
                        float* __restrict__ ea_csr) {
  int idx = blockIdx.x * blockDim.x + threadIdx.x;  // (p, quad)
  if (idx >= NE * 4) return;
  int p = idx >> 2, q = idx & 3;
  const float4* sp = (const float4*)(eattr + (size_t)csr_eid[p] * ED);
  ((float4*)(ea_csr + (size_t)p * ED))[q] = sp[q];
}

// ---- loop_attr = mean of incoming edge_attr; reads ea_csr CONTIGUOUSLY ----
__global__ __launch_bounds__(256) void k_loopattr(const float* __restrict__ ea_csr,
                                                  const int* __restrict__ rowptr,
                                                  float* __restrict__ loop_attr) {
  int wave = threadIdx.x >> 6, lane = threadIdx.x & 63;
  int d = blockIdx.x * 4 + wave;
  if (d >= NN) return;
  int g = lane >> 4, k = lane & 15;
  int b = rowptr[d], n = rowptr[d + 1] - b;
  float s = 0.f;
  for (int i = g; i < n; i += 4)
    s += ea_csr[(size_t)(b + i) * ED + k];   // contiguous CSR rows
  s += __shfl_xor(s, 16, 64);
  s += __shfl_xor(s, 32, 64);
  if (g == 0) loop_attr[d * ED + k] = s / fmaxf((float)n, 1.0f);
}

// ---- Wpk for ALL 3 layers in one dispatch ----
// Wpk[l][((h*32 + cp)*16 + k)*2 + j] = We_l[k][h*64 + 2*cp + j]
__global__ void k_wet3(const float* __restrict__ We0, const float* __restrict__ We1,
                       const float* __restrict__ We2, float* __restrict__ Wpk) {
  int i = blockIdx.x * blockDim.x + threadIdx.x;
  if (i >= 3 * ED * HC) return;
  int l = i / (ED * HC);
  int r = i - l * (ED * HC);
  const float* We = (l == 0) ? We0 : (l == 1) ? We1 : We2;
  int j  = r & 1;
  int k  = (r >> 1) & 15;
  int cp = (r >> 5) & 31;
  int h  = r >> 10;
  Wpk[i] = We[k * HC + h * CD + cp * 2 + j];
}

// ---- xl = h @ Wl + bl  (node-major xl[node][hc], contiguous 1280B rows) ----
template <int D>
__global__ __launch_bounds__(320) void k_xl(const float* __restrict__ h,
                                            const float* __restrict__ Wl,
                                            const float* __restrict__ bl,
                                            float* __restrict__ xl) {
  constexpr int NPB = 8;
  int node0 = blockIdx.x * NPB;
  int t = threadIdx.x;  // output column 0..319
  float acc[NPB];
  #pragma unroll
  for (int i = 0; i < NPB; i++) acc[i] = 0.f;
  for (int k = 0; k < D; k += 4) {
    float w0 = Wl[(k + 0) * HC + t];
    float w1 = Wl[(k + 1) * HC + t];
    float w2 = Wl[(k + 2) * HC + t];
    float w3 = Wl[(k + 3) * HC + t];
    #pragma unroll
    for (int i = 0; i < NPB; i++) {
      float4 hv = *(const float4*)(h + (size_t)(node0 + i) * D + k);
      acc[i] += hv.x * w0 + hv.y * w1 + hv.z * w2 + hv.w * w3;
    }
  }
  float bv = bl[t];
  #pragma unroll
  for (int i = 0; i < NPB; i++)
    xl[(size_t)(node0 + i) * HC + t] = acc[i] + bv;
}

// ---- scores: ONE THREAD PER (EDGE, HEAD); writes w = exp(clamped score).
// R14 packed body; node-major xl addressing; head-clustered XCD mapping
// (per-XCD line working set = one head's 2.56MB of lines -> L2-resident).
__global__ __launch_bounds__(256) void k_score(
    const int* __restrict__ csr_src, const int* __restrict__ csr_dst,
    const float* __restrict__ ea_csr, const float* __restrict__ loop_attr,
    const float* __restrict__ xl, const float* __restrict__ Wpk,
    const float* __restrict__ att, float* __restrict__ wP) {
  int bid = blockIdx.x;                       // 0..TOTB-1
  int w = (bid & 7) * PERX + (bid >> 3);      // work item, contiguous per XCD
  int h = w / PB;                             // head (uniform, magic-div)
  int lb = w - h * PB;                        // p-slice within head
  int p = lb * 256 + threadIdx.x;
  if (p >= EF) return;
  int s, d;
  const float* ea;
  if (p < NE) { s = csr_src[p]; d = csr_dst[p]; ea = ea_csr + (size_t)p * ED; }
  else        { s = d = p - NE; ea = loop_attr + (size_t)(p - NE) * ED; }
  float eas[16];
  {
    const float4* q = (const float4*)ea;
    float4 t0 = q[0], t1 = q[1], t2 = q[2], t3 = q[3];
    eas[0] = t0.x;  eas[1] = t0.y;  eas[2] = t0.z;  eas[3] = t0.w;
    eas[4] = t1.x;  eas[5] = t1.y;  eas[6] = t1.z;  eas[7] = t1.w;
    eas[8] = t2.x;  eas[9] = t2.y;  eas[10] = t2.z; eas[11] = t2.w;
    eas[12] = t3.x; eas[13] = t3.y; eas[14] = t3.z; eas[15] = t3.w;
  }
  const float* xsrow = xl + (size_t)s * HC + h * CD;   // node-major
  const float* xdrow = xl + (size_t)d * HC + h * CD;
  const f2* wp = (const f2*)Wpk + (size_t)h * (CD / 2) * ED;  // [32 pairs][16 k]
  const f2* ap = (const f2*)(att + (size_t)h * CD);           // pairs contiguous
  f2 sc2 = {0.f, 0.f};
  const f2 zero = {0.f, 0.f};
  #pragma unroll 4
  for (int cb = 0; cb < CD; cb += 4) {  // 2 channel-pairs per iter, 16 iters
    int cp = cb >> 1;
    float4 xs4 = *(const float4*)(xsrow + cb);
    float4 xd4 = *(const float4*)(xdrow + cb);
    const f2* w0 = wp + (size_t)cp * ED;
    const f2* w1 = w0 + ED;
    f2 z0 = f2{xs4.x, xs4.y} + f2{xd4.x, xd4.y};   // v_pk_add_f32
    f2 z1 = f2{xs4.z, xs4.w} + f2{xd4.z, xd4.w};
    #pragma unroll
    for (int k = 0; k < ED; k++) {                 // 2x v_pk_fma_f32 per k
      z0 += w0[k] * eas[k];
      z1 += w1[k] * eas[k];
    }
    // leaky: max(z,0) + NEG*min(z,0)  (packed, branchless, exact)
    z0 = __builtin_elementwise_max(z0, zero) + NEG * __builtin_elementwise_min(z0, zero);
    z1 = __builtin_elementwise_max(z1, zero) + NEG * __builtin_elementwise_min(z1, zero);
    sc2 += z0 * ap[cp];
    sc2 += z1 * ap[cp + 1];
  }
  float sc = sc2.x + sc2.y;
  sc = fminf(fmaxf(sc, -60.f), 60.f);  // clamp never binds for sane inputs
  wP[(size_t)h * EFP + p] = __expf(sc);
}

// ---- aggregation: block per node, wave per head; 8-wide load batching ----
// 8 src + 8 w + 8 xs gathers issued into named regs before use -> 8 VMEM in
// flight (R22's 4-wide/VGPR=16 form serialized on register reuse).
__global__ __launch_bounds__(320) void k_agg(
    const int* __restrict__ csr_src, const int* __restrict__ rowptr,
    const float* __restrict__ wP, const float* __restrict__ xl,
    const float* __restrict__ bias, float* __restrict__ out) {
  __shared__ float s_v[NH][CD];
  int h = threadIdx.x >> 6, lane = threadIdx.x & 63;
  int d = blockIdx.x;
  int b = rowptr[d], pe = rowptr[d + 1];
  const float* sp = wP + (size_t)h * EFP;
  const float* xlh = xl + h * CD + lane;               // node-major layout
  // self loop init
  float dn = sp[NE + d];
  float acc = dn * xlh[(size_t)d * HC];
  int p = b;
  // 8-edge batches: all 8 gathers independent and in flight together
  for (; p + 8 <= pe; p += 8) {
    int s0 = csr_src[p + 0], s1 = csr_src[p + 1];
    int s2 = csr_src[p + 2], s3 = csr_src[p + 3];
    int s4 = csr_src[p + 4], s5 = csr_src[p + 5];
    int s6 = csr_src[p + 6], s7 = csr_src[p + 7];
    float w0 = sp[p + 0], w1 = sp[p + 1], w2 = sp[p + 2], w3 = sp[p + 3];
    float w4 = sp[p + 4], w5 = sp[p + 5], w6 = sp[p + 6], w7 = sp[p + 7];
    float x0 = xlh[(size_t)s0 * HC];
    float x1 = xlh[(size_t)s1 * HC];
    float x2 = xlh[(size_t)s2 * HC];
    float x3 = xlh[(size_t)s3 * HC];
    float x4 = xlh[(size_t)s4 * HC];
    float x5 = xlh[(size_t)s5 * HC];
    float x6 = xlh[(size_t)s6 * HC];
    float x7 = xlh[(size_t)s7 * HC];
    dn += ((w0 + w1) + (w2 + w3)) + ((w4 + w5) + (w6 + w7));
    acc += ((w0 * x0 + w1 * x1) + (w2 * x2 + w3 * x3)) +
           ((w4 * x4 + w5 * x5) + (w6 * x6 + w7 * x7));
  }
  for (; p + 4 <= pe; p += 4) {
    int s0 = csr_src[p + 0], s1 = csr_src[p + 1];
    int s2 = csr_src[p + 2], s3 = csr_src[p + 3];
    float w0 = sp[p + 0], w1 = sp[p + 1], w2 = sp[p + 2], w3 = sp[p + 3];
    float x0 = xlh[(size_t)s0 * HC];
    float x1 = xlh[(size_t)s1 * HC];
    float x2 = xlh[(size_t)s2 * HC];
    float x3 = xlh[(size_t)s3 * HC];
    dn += (w0 + w1) + (w2 + w3);
    acc += (w0 * x0 + w1 * x1) + (w2 * x2 + w3 * x3);
  }
  for (; p < pe; p++) {
    int s0 = csr_src[p];
    float w0 = sp[p];
    dn += w0;
    acc += w0 * xlh[(size_t)s0 * HC];
  }
  s_v[h][lane] = acc / dn;
  __syncthreads();
  if (h == 0) {
    float v = s_v[0][lane] + s_v[1][lane] + s_v[2][lane] + s_v[3][lane] + s_v[4][lane];
    v = v * (1.0f / NH) + bias[lane];
    v = v > 0.f ? v : expm1f(v);
    out[(size_t)d * CD + lane] = v;
  }
}

static inline size_t aln(size_t x) { return (x + 255) & ~(size_t)255; }

extern "C" void kernel_launch(void* const* d_in, const int* in_sizes, int n_in,
                              void* d_out, int out_size, void* d_ws, size_t ws_size,
                              hipStream_t stream) {
  const float* x = (const float*)d_in[0];
  const int* ei = (const int*)d_in[1];      // [2, NE]: src row then dst row
  const float* eattr = (const float*)d_in[2];

  char* w = (char*)d_ws;
  int* degi      = (int*)w;                 w += aln(NN * 4);
  int* cursor    = (int*)w;                 w += aln(NN * 4);
  int* rowptr    = (int*)w;                 w += aln((NN + 1) * 4);
  int* csr_eid   = (int*)w;                 w += aln((size_t)NE * 4);
  int* csr_src   = (int*)w;                 w += aln((size_t)NE * 4);
  int* csr_dst   = (int*)w;                 w += aln((size_t)NE * 4);
  float* loop_attr = (float*)w;             w += aln((size_t)NN * ED * 4);
  float* ea_csr  = (float*)w;               w += aln((size_t)NE * ED * 4);
  float* xl      = (float*)w;               w += aln((size_t)NN * HC * 4);
  float* wPbuf   = (float*)w;               w += aln((size_t)NH * EFP * 4);
  float* Wpk     = (float*)w;               w += aln((size_t)3 * ED * HC * 4);
  float* hbuf    = (float*)w;               w += aln((size_t)NN * CD * 4);

  // graph structure + permuted edge attrs + all-layer Wpk (layer-invariant)
  hipMemsetAsync(degi, 0, NN * 4, stream);
  hipMemsetAsync(cursor, 0, NN * 4, stream);
  k_count<<<(NE + 255) / 256, 256, 0, stream>>>(ei + NE, degi);
  k_scan<<<1, 1024, 0, stream>>>(degi, rowptr);
  k_fill<<<(NE + 255) / 256, 256, 0, stream>>>(ei, rowptr, cursor, csr_eid, csr_src, csr_dst);
  k_eacsr<<<(NE * 4 + 255) / 256, 256, 0, stream>>>(csr_eid, eattr, ea_csr);
  k_loopattr<<<(NN + 3) / 4, 256, 0, stream>>>(ea_csr, rowptr, loop_attr);
  k_wet3<<<(3 * ED * HC + 255) / 256, 256, 0, stream>>>(
      (const float*)d_in[5], (const float*)d_in[10], (const float*)d_in[15], Wpk);

  for (int l = 0; l < 3; l++) {
    const float* Wl  = (const float*)d_in[3 + 5 * l];
    const float* bl  = (const float*)d_in[4 + 5 * l];
    const float* att = (const float*)d_in[6 + 5 * l];
    const float* b   = (const float*)d_in[7 + 5 * l];

    if (l == 0) k_xl<ND><<<NN / 8, 320, 0, stream>>>(x, Wl, bl, xl);
    else        k_xl<CD><<<NN / 8, 320, 0, stream>>>(hbuf, Wl, bl, xl);

    k_score<<<TOTB, 256, 0, stream>>>(csr_src, csr_dst, ea_csr, loop_attr,
                                      xl, Wpk + (size_t)l * ED * HC, att, wPbuf);

    float* dst_out = (l < 2) ? hbuf : (float*)d_out;
    k_agg<<<NN, 320, 0, stream>>>(csr_src, rowptr, wPbuf, xl, b, dst_out);
  }
}